// Round 4
// baseline (1472.330 us; speedup 1.0000x reference)
//
#include <hip/hip_runtime.h>

#define N_PTS   200000
#define CIN     64
#define COUT    16
#define KK      27
#define SXD     998
#define SYD     998
#define SZD     38
#define STRX    (SYD*SZD)        /* 37924 */
#define SENTV   (SXD*SYD*SZD)    /* 37848152 */
#define NKTOT   (N_PTS*KK)       /* 5400000 */
#define NWORDS  ((SENTV+31)/32)  /* 1182755 */
#define NCHUNK  ((NWORDS+255)/256) /* 4621 */
#define NB      16000            /* (x>>3)*128+(y>>3), x,y<1000 */

typedef float f32x4 __attribute__((ext_vector_type(4)));

// ---------------- K1: mark occupied voxels (+optional bucket histogram) ------------
// The 3 z-offsets of one (ox,oy) are consecutive bits -> one atomicOr of up to 3 bits.
__global__ void mark_kernel(const int* __restrict__ coords, unsigned* __restrict__ bm,
                            unsigned* __restrict__ mu, unsigned* __restrict__ hist) {
    int n = blockIdx.x * blockDim.x + threadIdx.x;
    if (n >= N_PTS) return;
    int4 c = ((const int4*)coords)[n];
    int x = c.y, y = c.z, z = c.w;
    if (hist) {
        unsigned key = ((unsigned)x >> 3) * 128u + ((unsigned)y >> 3);
        atomicAdd(&hist[key], 1u);
    }
    int zlo = z - 2; if (zlo < 0) zlo = 0;
    int zhi = z;     if (zhi > SZD - 1) zhi = SZD - 1;
    unsigned nb = (unsigned)(zhi - zlo + 1);      // 1..3
    unsigned mseed = (1u << nb) - 1u;
    #pragma unroll
    for (int dx = 0; dx < 3; dx++) {
        int ox = x - dx;
        if (ox < 0 || ox >= SXD) continue;
        #pragma unroll
        for (int dy = 0; dy < 3; dy++) {
            int oy = y - dy;
            if (oy < 0 || oy >= SYD) continue;
            int lin = ox*STRX + oy*SZD + zlo;
            unsigned w = (unsigned)lin >> 5;
            unsigned b = (unsigned)lin & 31u;
            unsigned lowm = mseed << b;           // truncation = low-word part
            unsigned old = atomicOr(&bm[w], lowm);
            unsigned col = old & lowm;
            if (col) atomicOr(&mu[w], col);
            if (b + nb > 32u) {                   // b >= 30 here
                unsigned highm = mseed >> (32u - b);
                unsigned old2 = atomicOr(&bm[w+1], highm);
                unsigned col2 = old2 & highm;
                if (col2) atomicOr(&mu[w+1], col2);
            }
        }
    }
}

// ---------------- K2: per-256-word chunk popcount sums ----------------
__global__ void chunk_sums_kernel(const unsigned* __restrict__ bm, unsigned* __restrict__ csums) {
    int w = blockIdx.x * 256 + threadIdx.x;
    unsigned c = (w < NWORDS) ? (unsigned)__popc(bm[w]) : 0u;
    __shared__ unsigned s[256];
    s[threadIdx.x] = c;
    __syncthreads();
    for (int off = 128; off > 0; off >>= 1) {
        if (threadIdx.x < off) s[threadIdx.x] += s[threadIdx.x + off];
        __syncthreads();
    }
    if (threadIdx.x == 0) csums[blockIdx.x] = s[0];
}

// ---------------- K3: two parallel single-block scans: csums->cprefix/U, hist->bpos -
__global__ void scan_all_kernel(const unsigned* __restrict__ csums,
                                unsigned* __restrict__ cprefix,
                                unsigned* __restrict__ Uptr,
                                const unsigned* __restrict__ hist,
                                unsigned* __restrict__ bpos,
                                int do_buckets) {
    __shared__ unsigned s[256];
    __shared__ unsigned run_s;
    if (blockIdx.x == 1 && !do_buckets) return;
    const unsigned* src = (blockIdx.x == 0) ? csums : hist;
    unsigned* dst       = (blockIdx.x == 0) ? cprefix : bpos;
    int count           = (blockIdx.x == 0) ? NCHUNK : NB;
    if (threadIdx.x == 0) run_s = 0;
    __syncthreads();
    for (int base = 0; base < count; base += 256) {
        int i = base + threadIdx.x;
        unsigned v = (i < count) ? src[i] : 0u;
        s[threadIdx.x] = v;
        __syncthreads();
        for (int off = 1; off < 256; off <<= 1) {
            unsigned t = (threadIdx.x >= off) ? s[threadIdx.x - off] : 0u;
            __syncthreads();
            s[threadIdx.x] += t;
            __syncthreads();
        }
        unsigned run = run_s;
        if (i < count) dst[i] = run + s[threadIdx.x] - v;
        unsigned tile_total = s[255];
        __syncthreads();
        if (threadIdx.x == 255) run_s = run + tile_total;
        __syncthreads();
    }
    if (blockIdx.x == 0 && threadIdx.x == 0) Uptr[0] = run_s;
}

// ---------------- K4: per-word exclusive prefix into wp ----------------
__global__ void word_prefix_kernel(const unsigned* __restrict__ bm,
                                   const unsigned* __restrict__ cprefix,
                                   unsigned* __restrict__ wp) {
    int w = blockIdx.x * 256 + threadIdx.x;
    unsigned v = (w < NWORDS) ? (unsigned)__popc(bm[w]) : 0u;
    __shared__ unsigned s[256];
    s[threadIdx.x] = v;
    __syncthreads();
    for (int off = 1; off < 256; off <<= 1) {
        unsigned t = (threadIdx.x >= off) ? s[threadIdx.x - off] : 0u;
        __syncthreads();
        s[threadIdx.x] += t;
        __syncthreads();
    }
    if (w < NWORDS) wp[w] = cprefix[blockIdx.x] + s[threadIdx.x] - v;
}

// ---------------- K4b: counting-sort scatter; carry point id in .x ------------------
__global__ void pidx_kernel(const int* __restrict__ coords, unsigned* __restrict__ bpos,
                            int4* __restrict__ csorted) {
    int n = blockIdx.x * blockDim.x + threadIdx.x;
    if (n >= N_PTS) return;
    int4 c = ((const int4*)coords)[n];
    unsigned key = ((unsigned)c.y >> 3) * 128u + ((unsigned)c.z >> 3);
    unsigned pos = atomicAdd(&bpos[key], 1u);
    csorted[pos] = make_int4(n, c.y, c.z, c.w);
}

// ---------------- fallback-path fills (ws too small) ----------------
__global__ void fill_out_kernel(float* __restrict__ out, const float* __restrict__ bias,
                                const unsigned* __restrict__ Uptr) {
    unsigned U = Uptr[0];
    unsigned i = blockIdx.x * blockDim.x + threadIdx.x;  // quarter-row index
    if (i >= (unsigned)NKTOT * 4u) return;
    unsigned row = i >> 2;
    int q = i & 3;
    float4 v;
    if (row < U) v = ((const float4*)bias)[q];
    else         v = make_float4(0.f, 0.f, 0.f, 0.f);
    ((float4*)out)[i] = v;
}

__global__ void fill_uniq_kernel(float* __restrict__ uniq) {
    unsigned i = blockIdx.x * blockDim.x + threadIdx.x;
    if (i < (unsigned)NKTOT) uniq[i] = (float)SENTV;
}

// ---------------- K5 (fast path): zeros + SENT only for tail rows >= U -------------
__global__ void tail_kernel(float* __restrict__ out, float* __restrict__ uniq,
                            const unsigned* __restrict__ Uptr) {
    unsigned U = Uptr[0];
    unsigned i = blockIdx.x * blockDim.x + threadIdx.x;   // row index
    if (i >= (unsigned)NKTOT || i < U) return;
    f32x4 z4 = {0.f, 0.f, 0.f, 0.f};
    f32x4* dst = (f32x4*)(out + (size_t)i * COUT);
    #pragma unroll
    for (int q = 0; q < 4; q++) __builtin_nontemporal_store(z4, dst + q);
    __builtin_nontemporal_store((float)SENTV, uniq + i);
}

// ---------------- K6: uniq ids via LDS (coalesced); bias-init multi rows ------------
template<bool DO_BIAS>
__global__ void write_uniq_kernel(const unsigned* __restrict__ bm,
                                  const unsigned* __restrict__ mu,
                                  const unsigned* __restrict__ wp,
                                  const unsigned* __restrict__ Uptr,
                                  float* __restrict__ uniq,
                                  float* __restrict__ out,
                                  const float* __restrict__ bias) {
    __shared__ float sbuf[8192];                 // max 256 words * 32 bits
    unsigned U = Uptr[0];
    int wfirst = blockIdx.x * 256;
    int wnext  = wfirst + 256;
    unsigned r0 = wp[wfirst];                    // wfirst < NWORDS by grid construction
    unsigned r1 = (wnext < NWORDS) ? wp[wnext] : U;
    int w = wfirst + threadIdx.x;
    unsigned bits = 0, r = 0, mbits = 0;
    if (w < NWORDS) {
        bits = bm[w];
        r    = wp[w];
        if (DO_BIAS) mbits = mu[w];
    }
    unsigned bb = bits, rr = r;
    while (bb) {
        int b = __ffs(bb) - 1;
        bb &= bb - 1;
        sbuf[rr - r0] = (float)((unsigned)w * 32u + b);
        rr++;
    }
    __syncthreads();
    unsigned span = r1 - r0;
    for (unsigned j = threadIdx.x; j < span; j += 256)
        __builtin_nontemporal_store(sbuf[j], uniq + r0 + j);
    if (DO_BIAS && bits && mbits) {
        f32x4 bv[4];
        #pragma unroll
        for (int q = 0; q < 4; q++) bv[q] = ((const f32x4*)bias)[q];
        bb = bits; rr = r;
        while (bb) {
            int b = __ffs(bb) - 1;
            bb &= bb - 1;
            if ((mbits >> b) & 1u) {
                f32x4* dst = (f32x4*)(out + (size_t)rr * COUT);
                #pragma unroll
                for (int q = 0; q < 4; q++) __builtin_nontemporal_store(bv[q], dst + q);
            }
            rr++;
        }
    }
}

// ---------------- K7: main scatter GEMV --------------------------------------------
// One thread = one point, all 27 taps. Per (dx,dy) column: ONE meta probe; the <=3
// valid z-taps are consecutive bits -> consecutive ranks r0,r0+1,r0+2 -> this thread
// writes a contiguous <=192B run (line self-coverage). All 9 columns' metadata is
// prefetched up-front into registers for memory-level parallelism.
template<bool SORTED>
__launch_bounds__(256)
__global__ void scatter_mm_kernel(const float* __restrict__ feats,
                                  const int4* __restrict__ cpts,
                                  const float* __restrict__ W,
                                  const float* __restrict__ bias,
                                  const unsigned* __restrict__ bm,
                                  const unsigned* __restrict__ mu,
                                  const unsigned* __restrict__ wp,
                                  float* __restrict__ out) {
    int i = blockIdx.x * 256 + threadIdx.x;
    if (i >= N_PTS) return;
    int4 cc = cpts[i];
    int n = SORTED ? cc.x : i;
    int x = cc.y, y = cc.z, z = cc.w;

    int zlo = z - 2; if (zlo < 0) zlo = 0;

    // ---- prefetch all 9 column metadata (registers; ~30 loads in flight) ----
    unsigned bmv[9], muv[9], mu2v[9], wpv[9], b0v[9];
    bool valv[9];
    #pragma unroll
    for (int dx = 0; dx < 3; dx++) {
        int ox = x - dx;
        #pragma unroll
        for (int dy = 0; dy < 3; dy++) {
            int k = dx*3 + dy;
            int oy = y - dy;
            bool v = (ox >= 0) & (ox < SXD) & (oy >= 0) & (oy < SYD);
            valv[k] = v;
            unsigned lin0 = (unsigned)(ox*STRX + oy*SZD + zlo);
            unsigned w0 = v ? (lin0 >> 5) : 0u;
            b0v[k] = lin0 & 31u;
            bmv[k]  = v ? bm[w0] : 0u;
            muv[k]  = v ? mu[w0] : 0u;
            mu2v[k] = (v && (lin0 & 31u) >= 30u) ? mu[w0 + 1] : 0u;
            wpv[k]  = v ? wp[w0] : 0u;
        }
    }

    // feature row in registers (16 float4 = 64 VGPRs)
    f32x4 f[CIN/4];
    const f32x4* fin4 = (const f32x4*)(feats + (size_t)n * CIN);
    #pragma unroll
    for (int q = 0; q < CIN/4; q++) f[q] = fin4[q];

    f32x4 bv[4];
    #pragma unroll
    for (int q = 0; q < 4; q++) bv[q] = ((const f32x4*)bias)[q];

    #pragma unroll 1
    for (int dx = 0; dx < 3; dx++) {
        #pragma unroll 1
        for (int dy = 0; dy < 3; dy++) {
            int k = dx*3 + dy;
            if (!valv[k]) continue;
            unsigned b0 = b0v[k];
            unsigned r0 = wpv[k] + (unsigned)__popc(bmv[k] & ((1u << b0) - 1u));
            unsigned mlo = muv[k], mhi = mu2v[k];
            #pragma unroll
            for (int dz = 0; dz < 3; dz++) {           // m compile-time per (dx,dy,dz)
                int oz = z - dz;
                if (oz < 0 || oz >= SZD) continue;
                unsigned j = (unsigned)(oz - zlo);     // 0..2; rank(oz) = r0 + j
                unsigned bb = b0 + j;
                bool ismul = (((bb < 32u) ? (mlo >> bb) : (mhi >> (bb - 32u))) & 1u) != 0u;
                unsigned rank = r0 + j;

                const float* wk = W + (size_t)(dx*9 + dy*3 + dz) * (CIN*COUT); // uniform
                float acc[COUT];
                #pragma unroll
                for (int o = 0; o < COUT; o++) acc[o] = 0.f;
                #pragma unroll
                for (int c4 = 0; c4 < CIN/4; c4++) {
                    f32x4 fv = f[c4];
                    const float* wrow = wk + c4 * 4 * COUT;
                    #pragma unroll
                    for (int o = 0; o < COUT; o++) {
                        acc[o] += fv.x * wrow[o] + fv.y * wrow[COUT + o]
                                + fv.z * wrow[2*COUT + o] + fv.w * wrow[3*COUT + o];
                    }
                }

                float* dst = out + (size_t)rank * COUT;
                if (!ismul) {
                    #pragma unroll
                    for (int q = 0; q < 4; q++) {
                        f32x4 vv;
                        vv.x = acc[q*4+0] + bv[q].x;
                        vv.y = acc[q*4+1] + bv[q].y;
                        vv.z = acc[q*4+2] + bv[q].z;
                        vv.w = acc[q*4+3] + bv[q].w;
                        ((f32x4*)dst)[q] = vv;
                    }
                } else {
                    #pragma unroll
                    for (int o = 0; o < COUT; o++) atomicAdd(dst + o, acc[o]);
                }
            }
        }
    }
}

extern "C" void kernel_launch(void* const* d_in, const int* in_sizes, int n_in,
                              void* d_out, int out_size, void* d_ws, size_t ws_size,
                              hipStream_t stream) {
    const float* feats  = (const float*)d_in[0];
    const int*   coords = (const int*)d_in[1];
    const float* W      = (const float*)d_in[2];
    const float* bias   = (const float*)d_in[3];
    float* out  = (float*)d_out;
    float* uniq = out + (size_t)NKTOT * COUT;

    unsigned* ws = (unsigned*)d_ws;

    // ---- fast-path layout (packed arrays; bm,mu,hist contiguous for one memset) ----
    size_t o_bm      = 0;
    size_t o_mu      = o_bm + NWORDS;
    size_t o_hist    = o_mu + NWORDS;
    size_t o_wp      = o_hist + NB;
    size_t o_bpos    = o_wp + NWORDS;
    size_t o_csums   = o_bpos + NB;
    size_t o_cprefix = o_csums + NCHUNK;
    size_t o_Uptr    = o_cprefix + NCHUNK;
    size_t o_csort   = (o_Uptr + 1 + 3) & ~(size_t)3;   // int4-aligned
    size_t fast_words = o_csort + 4 * (size_t)N_PTS;

    if (ws_size >= fast_words * sizeof(unsigned)) {
        unsigned* bm      = ws + o_bm;
        unsigned* mu      = ws + o_mu;
        unsigned* hist    = ws + o_hist;
        unsigned* wp      = ws + o_wp;
        unsigned* bpos    = ws + o_bpos;
        unsigned* csums   = ws + o_csums;
        unsigned* cprefix = ws + o_cprefix;
        unsigned* Uptr    = ws + o_Uptr;
        int4*     csorted = (int4*)(ws + o_csort);

        hipMemsetAsync(bm, 0, (2 * (size_t)NWORDS + NB) * sizeof(unsigned), stream);
        mark_kernel<<<(N_PTS + 255) / 256, 256, 0, stream>>>(coords, bm, mu, hist);
        chunk_sums_kernel<<<NCHUNK, 256, 0, stream>>>(bm, csums);
        scan_all_kernel<<<2, 256, 0, stream>>>(csums, cprefix, Uptr, hist, bpos, 1);
        pidx_kernel<<<(N_PTS + 255) / 256, 256, 0, stream>>>(coords, bpos, csorted);
        word_prefix_kernel<<<NCHUNK, 256, 0, stream>>>(bm, cprefix, wp);
        write_uniq_kernel<true><<<NCHUNK, 256, 0, stream>>>(
            bm, mu, wp, Uptr, uniq, out, bias);
        tail_kernel<<<(NKTOT + 255) / 256, 256, 0, stream>>>(out, uniq, Uptr);
        scatter_mm_kernel<true><<<(N_PTS + 255) / 256, 256, 0, stream>>>(
            feats, csorted, W, bias, bm, mu, wp, out);
    } else {
        // fallback: mu aliased to bm -> every row treated as multi (pure atomics)
        unsigned* bm      = ws;
        unsigned* wp      = ws + NWORDS;
        unsigned* csums   = ws + 2 * (size_t)NWORDS;
        unsigned* cprefix = csums + NCHUNK;
        unsigned* Uptr    = cprefix + NCHUNK;

        hipMemsetAsync(bm, 0, (size_t)NWORDS * sizeof(unsigned), stream);
        mark_kernel<<<(N_PTS + 255) / 256, 256, 0, stream>>>(coords, bm, bm, nullptr);
        chunk_sums_kernel<<<NCHUNK, 256, 0, stream>>>(bm, csums);
        scan_all_kernel<<<2, 256, 0, stream>>>(csums, cprefix, Uptr, nullptr, nullptr, 0);
        word_prefix_kernel<<<NCHUNK, 256, 0, stream>>>(bm, cprefix, wp);
        fill_out_kernel<<<(NKTOT * 4 + 255) / 256, 256, 0, stream>>>(out, bias, Uptr);
        fill_uniq_kernel<<<(NKTOT + 255) / 256, 256, 0, stream>>>(uniq);
        write_uniq_kernel<false><<<NCHUNK, 256, 0, stream>>>(
            bm, bm, wp, Uptr, uniq, out, bias);
        scatter_mm_kernel<false><<<(N_PTS + 255) / 256, 256, 0, stream>>>(
            feats, (const int4*)coords, W, bias, bm, bm, wp, out);
    }
}